// Round 1
// baseline (269.502 us; speedup 1.0000x reference)
//
#include <hip/hip_runtime.h>

typedef __bf16 bf16_t;
typedef bf16_t bf16x8 __attribute__((ext_vector_type(8)));
typedef float f32x4 __attribute__((ext_vector_type(4)));
typedef unsigned short u16;
typedef u16 u16x8 __attribute__((ext_vector_type(8)));
typedef unsigned int u32;
typedef u32 u32x4 __attribute__((ext_vector_type(4)));

#define E_TOT 524288
#define MT 64
#define NBLK (E_TOT / MT)

// round-to-nearest-even f32 -> bf16
__device__ __forceinline__ u16 f2bf(float f) {
  u32 u = __builtin_bit_cast(u32, f);
  u += 0x7FFFu + ((u >> 16) & 1u);
  return (u16)(u >> 16);
}

__device__ __forceinline__ u16x8 pack8(f32x4 a, f32x4 b) {
  u16x8 p;
  p[0] = f2bf(a[0]); p[1] = f2bf(a[1]); p[2] = f2bf(a[2]); p[3] = f2bf(a[3]);
  p[4] = f2bf(b[0]); p[5] = f2bf(b[1]); p[6] = f2bf(b[2]); p[7] = f2bf(b[3]);
  return p;
}

// W1 [384][256] f32 -> W1T [256][384] bf16
__global__ void prep_w1t(const float* __restrict__ W1, u16* __restrict__ W1T) {
  int t = blockIdx.x * 256 + threadIdx.x;
  if (t < 256 * 384) {
    int n = t / 384, k = t % 384;
    W1T[t] = f2bf(W1[k * 256 + n]);
  }
}
// W2 [256][64] f32 -> W2T [64][256] bf16
__global__ void prep_w2t(const float* __restrict__ W2, u16* __restrict__ W2T) {
  int t = blockIdx.x * 256 + threadIdx.x;
  if (t < 64 * 256) {
    int n = t / 256, k = t % 256;
    W2T[t] = f2bf(W2[k * 64 + n]);
  }
}

// Fused: x = [src|dest|edge|u[batch]] (E x 384); h = relu(x@W1+b1); out = h@W2+b2
__global__ void __launch_bounds__(256) edge_fused(
    const float* __restrict__ src, const float* __restrict__ dst,
    const float* __restrict__ ea, const float* __restrict__ u,
    const int* __restrict__ batch, const u16* __restrict__ W1T,
    const float* __restrict__ b1, const u16* __restrict__ W2T,
    const float* __restrict__ b2, float* __restrict__ out)
{
  // 65536 B LDS, phase-overlaid:
  //  phase1: As[64][72] @ 0 (9216 B), Ws[256][72] @ 4608 u16 (36864 B)
  //  phase2: Hs[64][256] swz @ 0 (32768 B), W2s[64][256] swz @ 16384 u16 (32768 B)
  __shared__ __align__(16) u16 smem[32768];
  u16* As  = smem;
  u16* Ws  = smem + 4608;
  u16* Hs  = smem;
  u16* W2s = smem + 16384;

  const int t    = threadIdx.x;
  const int wid  = t >> 6;
  const int lane = t & 63;
  const int lr   = lane & 15;
  const int lg   = lane >> 4;
  const int e0   = blockIdx.x * MT;

  f32x4 acc[4][4];
  #pragma unroll
  for (int i = 0; i < 4; ++i)
    #pragma unroll
    for (int j = 0; j < 4; ++j)
      acc[i][j] = (f32x4){0.f, 0.f, 0.f, 0.f};

  const int r  = t >> 2;          // staging row 0..63
  const int cg = (t & 3) << 4;    // staging col base {0,16,32,48}

  #pragma unroll
  for (int kb = 0; kb < 6; ++kb) {
    __syncthreads();
    // ---- stage A chunk (64 rows x 64 k) f32 -> bf16 ----
    const float* rowp;
    if (kb < 2)       rowp = src + (e0 + r) * 128 + kb * 64;
    else if (kb < 4)  rowp = dst + (e0 + r) * 128 + (kb - 2) * 64;
    else if (kb == 4) rowp = ea + (e0 + r) * 64;
    else              rowp = u + batch[e0 + r] * 64;
    f32x4 v0 = *(const f32x4*)(rowp + cg + 0);
    f32x4 v1 = *(const f32x4*)(rowp + cg + 4);
    f32x4 v2 = *(const f32x4*)(rowp + cg + 8);
    f32x4 v3 = *(const f32x4*)(rowp + cg + 12);
    *(u16x8*)&As[r * 72 + cg + 0] = pack8(v0, v1);
    *(u16x8*)&As[r * 72 + cg + 8] = pack8(v2, v3);

    // ---- stage W1T chunk: Ws[n][kk] = W1T[n][kb*64+kk], 256 x 64 bf16 ----
    #pragma unroll
    for (int it = 0; it < 8; ++it) {
      int idx = t + it * 256;
      int n = idx >> 3, j = idx & 7;
      u32x4 d = *(const u32x4*)(W1T + n * 384 + kb * 64 + j * 8);
      *(u32x4*)&Ws[n * 72 + j * 8] = d;
    }
    __syncthreads();

    // ---- MFMA: 2 k-steps of 32 ----
    #pragma unroll
    for (int ks = 0; ks < 2; ++ks) {
      bf16x8 af[4], bfr[4];
      #pragma unroll
      for (int mf = 0; mf < 4; ++mf)
        af[mf] = *(const bf16x8*)&As[(mf * 16 + lr) * 72 + ks * 32 + lg * 8];
      #pragma unroll
      for (int nf = 0; nf < 4; ++nf)
        bfr[nf] = *(const bf16x8*)&Ws[(wid * 64 + nf * 16 + lr) * 72 + ks * 32 + lg * 8];
      #pragma unroll
      for (int mf = 0; mf < 4; ++mf)
        #pragma unroll
        for (int nf = 0; nf < 4; ++nf)
          acc[mf][nf] = __builtin_amdgcn_mfma_f32_16x16x32_bf16(af[mf], bfr[nf], acc[mf][nf], 0, 0, 0);
    }
  }
  __syncthreads();  // all Ws/As reads done before overwriting with Hs/W2s

  // ---- h = relu(acc + b1) -> Hs (XOR-swizzled [64][256]) ----
  float bias[4];
  #pragma unroll
  for (int nf = 0; nf < 4; ++nf) bias[nf] = b1[wid * 64 + nf * 16 + lr];
  #pragma unroll
  for (int mf = 0; mf < 4; ++mf)
    #pragma unroll
    for (int nf = 0; nf < 4; ++nf)
      #pragma unroll
      for (int rr = 0; rr < 4; ++rr) {
        int row = mf * 16 + lg * 4 + rr;
        int col = wid * 64 + nf * 16 + lr;
        float v = fmaxf(acc[mf][nf][rr] + bias[nf], 0.f);
        Hs[row * 256 + ((((col >> 3) ^ (row & 7)) << 3) | (col & 7))] = f2bf(v);
      }

  // ---- stage W2s (XOR-swizzled [64][256]): W2s[n][k] = W2T[n][k] ----
  #pragma unroll
  for (int it = 0; it < 8; ++it) {
    int idx = t + it * 256;
    int n = idx >> 5, j = idx & 31;
    u32x4 d = *(const u32x4*)(W2T + n * 256 + j * 8);
    *(u32x4*)&W2s[n * 256 + ((j ^ (n & 7)) << 3)] = d;
  }
  __syncthreads();

  // ---- layer 2: out_tile[64][64] = Hs @ W2 ----
  f32x4 acc2[4];
  #pragma unroll
  for (int nf = 0; nf < 4; ++nf) acc2[nf] = (f32x4){0.f, 0.f, 0.f, 0.f};
  const int rowA = wid * 16 + lr;
  #pragma unroll
  for (int ks = 0; ks < 8; ++ks) {
    bf16x8 a = *(const bf16x8*)&Hs[rowA * 256 + (((ks * 4 + lg) ^ (rowA & 7)) << 3)];
    #pragma unroll
    for (int nf = 0; nf < 4; ++nf) {
      int n = nf * 16 + lr;
      bf16x8 b = *(const bf16x8*)&W2s[n * 256 + (((ks * 4 + lg) ^ (n & 7)) << 3)];
      acc2[nf] = __builtin_amdgcn_mfma_f32_16x16x32_bf16(a, b, acc2[nf], 0, 0, 0);
    }
  }

  // ---- epilogue: out = acc2 + b2 (f32) ----
  #pragma unroll
  for (int nf = 0; nf < 4; ++nf) {
    float bb = b2[nf * 16 + lr];
    #pragma unroll
    for (int rr = 0; rr < 4; ++rr) {
      int row = e0 + wid * 16 + lg * 4 + rr;
      out[row * 64 + nf * 16 + lr] = acc2[nf][rr] + bb;
    }
  }
}

extern "C" void kernel_launch(void* const* d_in, const int* in_sizes, int n_in,
                              void* d_out, int out_size, void* d_ws, size_t ws_size,
                              hipStream_t stream) {
  const float* src  = (const float*)d_in[0];
  const float* dst  = (const float*)d_in[1];
  const float* ea   = (const float*)d_in[2];
  const float* u    = (const float*)d_in[3];
  const int* batch  = (const int*)d_in[4];
  const float* W1   = (const float*)d_in[5];
  const float* b1   = (const float*)d_in[6];
  const float* W2   = (const float*)d_in[7];
  const float* b2   = (const float*)d_in[8];
  float* out = (float*)d_out;

  u16* W1T = (u16*)d_ws;            // 256*384 bf16
  u16* W2T = W1T + 256 * 384;       // 64*256 bf16

  prep_w1t<<<(256 * 384 + 255) / 256, 256, 0, stream>>>(W1, W1T);
  prep_w2t<<<(64 * 256 + 255) / 256, 256, 0, stream>>>(W2, W2T);
  edge_fused<<<NBLK, 256, 0, stream>>>(src, dst, ea, u, batch, W1T, b1, W2T, b2, out);
}